// Round 6
// baseline (923.741 us; speedup 1.0000x reference)
//
#include <hip/hip_runtime.h>

#define H 256
#define LSEQ 200
#define NB 16
#define BL 3200           // NB * LSEQ
#define V1 50001
#define NPAD 50048        // V1 padded up to multiple of 64

#define GAS __attribute__((address_space(1)))
#define LAS __attribute__((address_space(3)))

typedef __attribute__((ext_vector_type(8))) short short8;
typedef __attribute__((ext_vector_type(4))) float f32x4;

__device__ __forceinline__ unsigned short f2bf(float f) {
    unsigned int u = __builtin_bit_cast(unsigned int, f);
    u += 0x7fffu + ((u >> 16) & 1u);   // round-to-nearest-even
    return (unsigned short)(u >> 16);
}

// ---------------- weight prep ----------------

__global__ void k_f32_to_bf16(const float* __restrict__ src,
                              unsigned short* __restrict__ dst, int n) {
    int i = blockIdx.x * blockDim.x + threadIdx.x;
    if (i < n) dst[i] = f2bf(src[i]);
}

// dst[i][h][m] = bf16(src[i][m][h])  -- 32x32 LDS tiles
__global__ __launch_bounds__(256) void k_transpose_bf(
    const float* __restrict__ src, unsigned short* __restrict__ dst) {
    __shared__ float t[32][33];
    int i = blockIdx.z;
    int m0 = blockIdx.x * 32, h0 = blockIdx.y * 32;
    int tx = threadIdx.x & 31, ty = threadIdx.x >> 5;   // 32 x 8
#pragma unroll
    for (int s = 0; s < 32; s += 8)
        t[ty + s][tx] = src[((size_t)i * 256 + m0 + ty + s) * 256 + h0 + tx];
    __syncthreads();
#pragma unroll
    for (int s = 0; s < 32; s += 8)
        dst[((size_t)i * 256 + h0 + ty + s) * 256 + m0 + tx] = f2bf(t[tx][ty + s]);
}

// item_emb f32 (V1 x H) -> bf16 (NPAD x H), pad rows zeroed. 4 elems/thread.
__global__ void k_conv_emb(const float* __restrict__ src, unsigned short* __restrict__ dst) {
    size_t i4 = (size_t)blockIdx.x * blockDim.x + threadIdx.x;
    size_t total4 = (size_t)NPAD * H / 4;
    if (i4 >= total4) return;
    size_t e0 = i4 * 4;
    size_t row = e0 >> 8;
    ushort4 o;
    if (row < V1) {
        float4 v = *(const float4*)(src + e0);
        o.x = f2bf(v.x); o.y = f2bf(v.y); o.z = f2bf(v.z); o.w = f2bf(v.w);
    } else {
        o.x = o.y = o.z = o.w = 0;
    }
    *(ushort4*)(dst + e0) = o;
}

// ---------------- LayerNorm kernels ----------------

__device__ __forceinline__ void block_reduce2(float& s, float& ss, float* red) {
#pragma unroll
    for (int off = 32; off > 0; off >>= 1) {
        s += __shfl_down(s, off);
        ss += __shfl_down(ss, off);
    }
    int t = threadIdx.x;
    if ((t & 63) == 0) { red[(t >> 6) * 2] = s; red[(t >> 6) * 2 + 1] = ss; }
    __syncthreads();
    s  = red[0] + red[2] + red[4] + red[6];
    ss = red[1] + red[3] + red[5] + red[7];
}

__global__ __launch_bounds__(256) void k_embed_ln(
    const int* __restrict__ ids, const float* __restrict__ emb,
    const float* __restrict__ pos, const float* __restrict__ g,
    const float* __restrict__ bta, float* __restrict__ xf,
    unsigned short* __restrict__ xb) {
    __shared__ float red[8];
    int bl = blockIdx.x;
    int h = threadIdx.x;
    int l = bl % LSEQ;
    int id = ids[bl];
    float val = emb[(size_t)id * H + h] * 16.0f + pos[(size_t)l * H + h];
    float s = val, ss = val * val;
    block_reduce2(s, ss, red);
    float mean = s * (1.0f / H);
    float var = fmaxf(ss * (1.0f / H) - mean * mean, 0.0f);
    float rs = rsqrtf(var + 1e-8f);
    float keep = (id != 0) ? 1.0f : 0.0f;
    float o = ((val - mean) * rs * g[h] + bta[h]) * keep;
    xf[(size_t)bl * H + h] = o;
    xb[(size_t)bl * H + h] = f2bf(o);
}

__global__ __launch_bounds__(256) void k_add_ln(
    const float* __restrict__ x, const float* __restrict__ d,
    const float* __restrict__ g, const float* __restrict__ bta,
    const int* __restrict__ ids, float* __restrict__ xf,
    unsigned short* __restrict__ xb) {
    __shared__ float red[8];
    int bl = blockIdx.x;
    int h = threadIdx.x;
    float val = x[(size_t)bl * H + h] + d[(size_t)bl * H + h];
    float s = val, ss = val * val;
    block_reduce2(s, ss, red);
    float mean = s * (1.0f / H);
    float var = fmaxf(ss * (1.0f / H) - mean * mean, 0.0f);
    float rs = rsqrtf(var + 1e-8f);
    float keep = (ids[bl] != 0) ? 1.0f : 0.0f;
    float o = ((val - mean) * rs * g[h] + bta[h]) * keep;
    xf[(size_t)bl * H + h] = o;
    xb[(size_t)bl * H + h] = f2bf(o);
}

// causal mean: in-place v[b,l,h] = (sum_{l'<=l} v[b,l',h]) / (l+1)
__global__ __launch_bounds__(64) void k_cumsum(float* __restrict__ v) {
    int b = blockIdx.x;
    int h = blockIdx.y * 64 + threadIdx.x;
    float* p = v + (size_t)b * LSEQ * H + h;
    float acc = 0.0f;
    for (int l = 0; l < LSEQ; l += 4) {
        float a0 = p[(size_t)(l + 0) * H];
        float a1 = p[(size_t)(l + 1) * H];
        float a2 = p[(size_t)(l + 2) * H];
        float a3 = p[(size_t)(l + 3) * H];
        acc += a0; p[(size_t)(l + 0) * H] = acc * (1.0f / (float)(l + 1));
        acc += a1; p[(size_t)(l + 1) * H] = acc * (1.0f / (float)(l + 2));
        acc += a2; p[(size_t)(l + 2) * H] = acc * (1.0f / (float)(l + 3));
        acc += a3; p[(size_t)(l + 3) * H] = acc * (1.0f / (float)(l + 4));
    }
}

// ---------------- small MFMA GEMM (H x H weights) ----------------
template<int BIAS, int RELU, int WF32, int WBF16>
__global__ __launch_bounds__(256) void k_gemm64(
    const unsigned short* __restrict__ A,
    const unsigned short* __restrict__ Bmat,
    const float* __restrict__ bias,
    float* __restrict__ outF,
    unsigned short* __restrict__ outB,
    int N, int K) {
    int bm = blockIdx.x * 64;
    int bn = blockIdx.y * 64;
    int tid = threadIdx.x;
    int w = tid >> 6, l = tid & 63;
    int wr = (w >> 1) * 32, wc = (w & 1) * 32;
    int l16 = l & 15, lk = (l >> 4) * 8;

    const unsigned short* Ap = A + (size_t)(bm + wr + l16) * K + lk;
    const unsigned short* Bp = Bmat + (size_t)(bn + wc + l16) * K + lk;

    f32x4 acc00 = {0.f,0.f,0.f,0.f}, acc01 = {0.f,0.f,0.f,0.f};
    f32x4 acc10 = {0.f,0.f,0.f,0.f}, acc11 = {0.f,0.f,0.f,0.f};

#pragma unroll
    for (int k0 = 0; k0 < 256; k0 += 32) {
        short8 a0 = *(const short8*)(Ap + k0);
        short8 a1 = *(const short8*)(Ap + (size_t)16 * K + k0);
        short8 b0 = *(const short8*)(Bp + k0);
        short8 b1 = *(const short8*)(Bp + (size_t)16 * K + k0);
        acc00 = __builtin_amdgcn_mfma_f32_16x16x32_bf16(a0, b0, acc00, 0, 0, 0);
        acc01 = __builtin_amdgcn_mfma_f32_16x16x32_bf16(a0, b1, acc01, 0, 0, 0);
        acc10 = __builtin_amdgcn_mfma_f32_16x16x32_bf16(a1, b0, acc10, 0, 0, 0);
        acc11 = __builtin_amdgcn_mfma_f32_16x16x32_bf16(a1, b1, acc11, 0, 0, 0);
    }

    int r0 = (l >> 4) * 4;
#pragma unroll
    for (int i = 0; i < 2; ++i) {
#pragma unroll
        for (int j = 0; j < 2; ++j) {
            f32x4 a = (i == 0) ? (j == 0 ? acc00 : acc01) : (j == 0 ? acc10 : acc11);
            int col = bn + wc + j * 16 + l16;
            float bv = BIAS ? bias[col] : 0.0f;
            int rowb = bm + wr + i * 16 + r0;
#pragma unroll
            for (int r = 0; r < 4; ++r) {
                float vv = a[r] + bv;
                if (RELU) vv = fmaxf(vv, 0.0f);
                size_t idx = (size_t)(rowb + r) * N + col;
                if (WF32) outF[idx] = vv;
                if (WBF16) outB[idx] = f2bf(vv);
            }
        }
    }
}

// ---------------- logits GEMM: streaming-store N-strips ----------------
// 32-col strip per block, B in regs (persistent), A single-buffered regs.
// Per M-tile program order: MFMA(af) -> load af(next tile) -> store acc.
// Stores NONTEMPORAL: the 640MB write-once stream must not thrash L2 (keeps
// the A panel L2-resident). Stores stay youngest in vmcnt order so the
// counted wait for next-tile loads never drains the store stream.
#define LGSTRIPS 1564                // NPAD / 32
#define LGWG (LGSTRIPS * 2)          // 3128, M split in halves (13 + 12 tiles)

__global__ __launch_bounds__(256, 4) void k_logits(
    const unsigned short* __restrict__ A,   // BL x 256 bf16
    const unsigned short* __restrict__ B,   // NPAD x 256 bf16
    float* __restrict__ out) {              // BL x V1 f32
    int bid = blockIdx.x;
    int strip = bid >> 1, half = bid & 1;
    int n0 = strip * 32;
    if (n0 >= V1) return;                   // fully-padded strip
    int mt0 = half ? 13 : 0;
    int mt1 = half ? 25 : 13;

    int tid = threadIdx.x;
    int w = tid >> 6, l = tid & 63;
    int wr = w * 32;               // wave's 32 rows within the 128-row tile
    int l16 = l & 15, lc = l >> 4;

    // B strip -> registers (persistent): rows n0 + j*16 + l16
    short8 breg[2][8];
#pragma unroll
    for (int j = 0; j < 2; ++j)
#pragma unroll
        for (int kt = 0; kt < 8; ++kt)
            breg[j][kt] = *(const short8*)(
                B + (size_t)(n0 + j * 16 + l16) * 256 + kt * 32 + lc * 8);

    // A fragments, single-buffered
    short8 af[2][8];
    auto loadA = [&](int mt) {
        const unsigned short* Abase =
            A + (size_t)(mt * 128 + wr + l16) * 256 + lc * 8;
#pragma unroll
        for (int i = 0; i < 2; ++i)
#pragma unroll
            for (int kt = 0; kt < 8; ++kt)
                af[i][kt] = *(const short8*)(Abase + (size_t)(i * 16) * 256 + kt * 32);
    };
    loadA(mt0);

    for (int mt = mt0; mt < mt1; ++mt) {
        f32x4 acc[2][2] = {};
        // compute (consumes af; WAR forces the reload below to stay after)
#pragma unroll
        for (int kt = 0; kt < 8; ++kt)
#pragma unroll
            for (int i = 0; i < 2; ++i)
#pragma unroll
                for (int j = 0; j < 2; ++j)
                    acc[i][j] = __builtin_amdgcn_mfma_f32_16x16x32_bf16(
                        af[i][kt], breg[j][kt], acc[i][j], 0, 0, 0);
        // prefetch next tile's A BEFORE the stores -> stores stay youngest
        if (mt + 1 < mt1) loadA(mt + 1);
        // stream out (nontemporal: keep L2 clean)
#pragma unroll
        for (int i = 0; i < 2; ++i) {
            int mrow = mt * 128 + wr + i * 16 + lc * 4;
#pragma unroll
            for (int j = 0; j < 2; ++j) {
                int n = n0 + j * 16 + l16;
                if (n < V1) {
#pragma unroll
                    for (int rg = 0; rg < 4; ++rg)
                        __builtin_nontemporal_store(
                            acc[i][j][rg], &out[(size_t)(mrow + rg) * V1 + n]);
                }
            }
        }
    }
}

// ---------------- driver ----------------

extern "C" void kernel_launch(void* const* d_in, const int* in_sizes, int n_in,
                              void* d_out, int out_size, void* d_ws, size_t ws_size,
                              hipStream_t stream) {
    const int*   ids      = (const int*)d_in[0];
    const float* item_emb = (const float*)d_in[1];
    const float* pos_emb  = (const float*)d_in[2];
    const float* emb_g    = (const float*)d_in[3];
    const float* emb_b    = (const float*)d_in[4];
    const float* Wv       = (const float*)d_in[5];
    const float* Wo       = (const float*)d_in[6];
    const float* attn_g   = (const float*)d_in[7];
    const float* attn_b   = (const float*)d_in[8];
    const float* W1       = (const float*)d_in[9];
    const float* b1       = (const float*)d_in[10];
    const float* W2       = (const float*)d_in[11];
    const float* b2       = (const float*)d_in[12];
    const float* ffn_g    = (const float*)d_in[13];
    const float* ffn_b    = (const float*)d_in[14];
    float* out = (float*)d_out;

    char* ws = (char*)d_ws;
    size_t off = 0;
    auto alloc = [&](size_t bytes) -> void* {
        void* p = ws + off;
        off += (bytes + 255) & ~(size_t)255;
        return p;
    };
    float* xf  = (float*)alloc((size_t)BL * H * 4);
    float* vbuf= (float*)alloc((size_t)BL * H * 4);
    float* y2  = (float*)alloc((size_t)BL * H * 4);
    unsigned short* xb  = (unsigned short*)alloc((size_t)BL * H * 2);
    unsigned short* y1b = (unsigned short*)alloc((size_t)BL * H * 2);
    unsigned short* WcB = (unsigned short*)alloc((size_t)2 * H * H * 2);
    unsigned short* W1B = (unsigned short*)alloc((size_t)2 * H * H * 2);
    unsigned short* W2B = (unsigned short*)alloc((size_t)2 * H * H * 2);
    unsigned short* WoB = (unsigned short*)alloc((size_t)2 * H * H * 2);
    unsigned short* WvT = (unsigned short*)alloc((size_t)2 * H * H * 2);
    unsigned short* embB= (unsigned short*)alloc((size_t)NPAD * H * 2);

    // --- prep ---
    k_f32_to_bf16<<<dim3(512), dim3(256), 0, stream>>>(W1, W1B, 2 * H * H);
    k_f32_to_bf16<<<dim3(512), dim3(256), 0, stream>>>(W2, W2B, 2 * H * H);
    k_f32_to_bf16<<<dim3(512), dim3(256), 0, stream>>>(Wo, WoB, 2 * H * H);
    k_transpose_bf<<<dim3(8, 8, 2), dim3(256), 0, stream>>>(Wv, WvT);
    {
        int n4 = NPAD * H / 4;
        k_conv_emb<<<dim3((n4 + 255) / 256), dim3(256), 0, stream>>>(item_emb, embB);
    }
    // Wc[i] = Wo[i] @ Wv[i]  via gemm64: A=WoB (o,m), B=WvT (h,m)
    for (int i = 0; i < 2; ++i)
        k_gemm64<0,0,0,1><<<dim3(4, 4), dim3(256), 0, stream>>>(
            WoB + (size_t)i * H * H, WvT + (size_t)i * H * H, nullptr,
            nullptr, WcB + (size_t)i * H * H, H, H);

    // --- embedding + LN ---
    k_embed_ln<<<dim3(BL), dim3(H), 0, stream>>>(ids, item_emb, pos_emb, emb_g, emb_b, xf, xb);

    // --- transformer blocks ---
    for (int i = 0; i < 2; ++i) {
        k_gemm64<0,0,1,0><<<dim3(BL / 64, H / 64), dim3(256), 0, stream>>>(
            xb, WcB + (size_t)i * H * H, nullptr, vbuf, nullptr, H, H);
        k_cumsum<<<dim3(NB, 4), dim3(64), 0, stream>>>(vbuf);
        k_add_ln<<<dim3(BL), dim3(H), 0, stream>>>(
            xf, vbuf, attn_g + (size_t)i * H, attn_b + (size_t)i * H, ids, xf, xb);
        k_gemm64<1,1,0,1><<<dim3(BL / 64, H / 64), dim3(256), 0, stream>>>(
            xb, W1B + (size_t)i * H * H, b1 + (size_t)i * H, nullptr, y1b, H, H);
        k_gemm64<1,0,1,0><<<dim3(BL / 64, H / 64), dim3(256), 0, stream>>>(
            y1b, W2B + (size_t)i * H * H, b2 + (size_t)i * H, y2, nullptr, H, H);
        k_add_ln<<<dim3(BL), dim3(H), 0, stream>>>(
            xf, y2, ffn_g + (size_t)i * H, ffn_b + (size_t)i * H, ids, xf, xb);
    }

    // --- logits = x @ item_emb^T ---
    k_logits<<<dim3(LGWG), dim3(256), 0, stream>>>(xb, embB, out);
}

// Round 7
// 787.295 us; speedup vs baseline: 1.1733x; 1.1733x over previous
//
#include <hip/hip_runtime.h>

#define H 256
#define LSEQ 200
#define NB 16
#define BL 3200           // NB * LSEQ
#define V1 50001
#define NPAD 50048        // V1 padded up to multiple of 64

#define GAS __attribute__((address_space(1)))
#define LAS __attribute__((address_space(3)))

typedef __attribute__((ext_vector_type(8))) short short8;
typedef __attribute__((ext_vector_type(4))) float f32x4;

__device__ __forceinline__ unsigned short f2bf(float f) {
    unsigned int u = __builtin_bit_cast(unsigned int, f);
    u += 0x7fffu + ((u >> 16) & 1u);   // round-to-nearest-even
    return (unsigned short)(u >> 16);
}

// ---------------- weight prep ----------------

__global__ void k_f32_to_bf16(const float* __restrict__ src,
                              unsigned short* __restrict__ dst, int n) {
    int i = blockIdx.x * blockDim.x + threadIdx.x;
    if (i < n) dst[i] = f2bf(src[i]);
}

// dst[i][h][m] = bf16(src[i][m][h])  -- 32x32 LDS tiles
__global__ __launch_bounds__(256) void k_transpose_bf(
    const float* __restrict__ src, unsigned short* __restrict__ dst) {
    __shared__ float t[32][33];
    int i = blockIdx.z;
    int m0 = blockIdx.x * 32, h0 = blockIdx.y * 32;
    int tx = threadIdx.x & 31, ty = threadIdx.x >> 5;   // 32 x 8
#pragma unroll
    for (int s = 0; s < 32; s += 8)
        t[ty + s][tx] = src[((size_t)i * 256 + m0 + ty + s) * 256 + h0 + tx];
    __syncthreads();
#pragma unroll
    for (int s = 0; s < 32; s += 8)
        dst[((size_t)i * 256 + h0 + ty + s) * 256 + m0 + tx] = f2bf(t[tx][ty + s]);
}

// item_emb f32 (V1 x H) -> bf16 (NPAD x H), pad rows zeroed. 4 elems/thread.
__global__ void k_conv_emb(const float* __restrict__ src, unsigned short* __restrict__ dst) {
    size_t i4 = (size_t)blockIdx.x * blockDim.x + threadIdx.x;
    size_t total4 = (size_t)NPAD * H / 4;
    if (i4 >= total4) return;
    size_t e0 = i4 * 4;
    size_t row = e0 >> 8;
    ushort4 o;
    if (row < V1) {
        float4 v = *(const float4*)(src + e0);
        o.x = f2bf(v.x); o.y = f2bf(v.y); o.z = f2bf(v.z); o.w = f2bf(v.w);
    } else {
        o.x = o.y = o.z = o.w = 0;
    }
    *(ushort4*)(dst + e0) = o;
}

// ---------------- LayerNorm kernels ----------------

__device__ __forceinline__ void block_reduce2(float& s, float& ss, float* red) {
#pragma unroll
    for (int off = 32; off > 0; off >>= 1) {
        s += __shfl_down(s, off);
        ss += __shfl_down(ss, off);
    }
    int t = threadIdx.x;
    if ((t & 63) == 0) { red[(t >> 6) * 2] = s; red[(t >> 6) * 2 + 1] = ss; }
    __syncthreads();
    s  = red[0] + red[2] + red[4] + red[6];
    ss = red[1] + red[3] + red[5] + red[7];
}

__global__ __launch_bounds__(256) void k_embed_ln(
    const int* __restrict__ ids, const float* __restrict__ emb,
    const float* __restrict__ pos, const float* __restrict__ g,
    const float* __restrict__ bta, float* __restrict__ xf,
    unsigned short* __restrict__ xb) {
    __shared__ float red[8];
    int bl = blockIdx.x;
    int h = threadIdx.x;
    int l = bl % LSEQ;
    int id = ids[bl];
    float val = emb[(size_t)id * H + h] * 16.0f + pos[(size_t)l * H + h];
    float s = val, ss = val * val;
    block_reduce2(s, ss, red);
    float mean = s * (1.0f / H);
    float var = fmaxf(ss * (1.0f / H) - mean * mean, 0.0f);
    float rs = rsqrtf(var + 1e-8f);
    float keep = (id != 0) ? 1.0f : 0.0f;
    float o = ((val - mean) * rs * g[h] + bta[h]) * keep;
    xf[(size_t)bl * H + h] = o;
    xb[(size_t)bl * H + h] = f2bf(o);
}

__global__ __launch_bounds__(256) void k_add_ln(
    const float* __restrict__ x, const float* __restrict__ d,
    const float* __restrict__ g, const float* __restrict__ bta,
    const int* __restrict__ ids, float* __restrict__ xf,
    unsigned short* __restrict__ xb) {
    __shared__ float red[8];
    int bl = blockIdx.x;
    int h = threadIdx.x;
    float val = x[(size_t)bl * H + h] + d[(size_t)bl * H + h];
    float s = val, ss = val * val;
    block_reduce2(s, ss, red);
    float mean = s * (1.0f / H);
    float var = fmaxf(ss * (1.0f / H) - mean * mean, 0.0f);
    float rs = rsqrtf(var + 1e-8f);
    float keep = (ids[bl] != 0) ? 1.0f : 0.0f;
    float o = ((val - mean) * rs * g[h] + bta[h]) * keep;
    xf[(size_t)bl * H + h] = o;
    xb[(size_t)bl * H + h] = f2bf(o);
}

// causal mean: in-place v[b,l,h] = (sum_{l'<=l} v[b,l',h]) / (l+1)
__global__ __launch_bounds__(64) void k_cumsum(float* __restrict__ v) {
    int b = blockIdx.x;
    int h = blockIdx.y * 64 + threadIdx.x;
    float* p = v + (size_t)b * LSEQ * H + h;
    float acc = 0.0f;
    for (int l = 0; l < LSEQ; l += 4) {
        float a0 = p[(size_t)(l + 0) * H];
        float a1 = p[(size_t)(l + 1) * H];
        float a2 = p[(size_t)(l + 2) * H];
        float a3 = p[(size_t)(l + 3) * H];
        acc += a0; p[(size_t)(l + 0) * H] = acc * (1.0f / (float)(l + 1));
        acc += a1; p[(size_t)(l + 1) * H] = acc * (1.0f / (float)(l + 2));
        acc += a2; p[(size_t)(l + 2) * H] = acc * (1.0f / (float)(l + 3));
        acc += a3; p[(size_t)(l + 3) * H] = acc * (1.0f / (float)(l + 4));
    }
}

// ---------------- small MFMA GEMM (H x H weights) ----------------
template<int BIAS, int RELU, int WF32, int WBF16>
__global__ __launch_bounds__(256) void k_gemm64(
    const unsigned short* __restrict__ A,
    const unsigned short* __restrict__ Bmat,
    const float* __restrict__ bias,
    float* __restrict__ outF,
    unsigned short* __restrict__ outB,
    int N, int K) {
    int bm = blockIdx.x * 64;
    int bn = blockIdx.y * 64;
    int tid = threadIdx.x;
    int w = tid >> 6, l = tid & 63;
    int wr = (w >> 1) * 32, wc = (w & 1) * 32;
    int l16 = l & 15, lk = (l >> 4) * 8;

    const unsigned short* Ap = A + (size_t)(bm + wr + l16) * K + lk;
    const unsigned short* Bp = Bmat + (size_t)(bn + wc + l16) * K + lk;

    f32x4 acc00 = {0.f,0.f,0.f,0.f}, acc01 = {0.f,0.f,0.f,0.f};
    f32x4 acc10 = {0.f,0.f,0.f,0.f}, acc11 = {0.f,0.f,0.f,0.f};

#pragma unroll
    for (int k0 = 0; k0 < 256; k0 += 32) {
        short8 a0 = *(const short8*)(Ap + k0);
        short8 a1 = *(const short8*)(Ap + (size_t)16 * K + k0);
        short8 b0 = *(const short8*)(Bp + k0);
        short8 b1 = *(const short8*)(Bp + (size_t)16 * K + k0);
        acc00 = __builtin_amdgcn_mfma_f32_16x16x32_bf16(a0, b0, acc00, 0, 0, 0);
        acc01 = __builtin_amdgcn_mfma_f32_16x16x32_bf16(a0, b1, acc01, 0, 0, 0);
        acc10 = __builtin_amdgcn_mfma_f32_16x16x32_bf16(a1, b0, acc10, 0, 0, 0);
        acc11 = __builtin_amdgcn_mfma_f32_16x16x32_bf16(a1, b1, acc11, 0, 0, 0);
    }

    int r0 = (l >> 4) * 4;
#pragma unroll
    for (int i = 0; i < 2; ++i) {
#pragma unroll
        for (int j = 0; j < 2; ++j) {
            f32x4 a = (i == 0) ? (j == 0 ? acc00 : acc01) : (j == 0 ? acc10 : acc11);
            int col = bn + wc + j * 16 + l16;
            float bv = BIAS ? bias[col] : 0.0f;
            int rowb = bm + wr + i * 16 + r0;
#pragma unroll
            for (int r = 0; r < 4; ++r) {
                float vv = a[r] + bv;
                if (RELU) vv = fmaxf(vv, 0.0f);
                size_t idx = (size_t)(rowb + r) * N + col;
                if (WF32) outF[idx] = vv;
                if (WBF16) outB[idx] = f2bf(vv);
            }
        }
    }
}

// ---------------- logits GEMM: persistent strips, B in LDS ----------------
// 64-col strip per block. B staged ONCE to LDS (32KB, source chunk-XOR
// swizzled, one barrier before any store exists). Main loop has NO barriers;
// per-kt B reads are ds_read (lgkmcnt) so the vmcnt stream is only
// {16 A-loads, then 32 stores} per tile -> the counted wait for A leaves a
// full 8KB store batch per wave outstanding. 16 waves/CU (VGPR<=128).
#define LGSTRIPS 782                 // NPAD / 64
#define LGWG (LGSTRIPS * 2)          // 1564, M split in halves (13 + 12 tiles)

__global__ __launch_bounds__(256, 4) void k_logits(
    const unsigned short* __restrict__ A,   // BL x 256 bf16
    const unsigned short* __restrict__ B,   // NPAD x 256 bf16
    float* __restrict__ out) {              // BL x V1 f32
    __shared__ unsigned short lB[64 * 256];  // 32KB

    int bid = blockIdx.x;
    int strip = bid >> 1, half = bid & 1;
    int n0 = strip * 64;
    int mt0 = half ? 13 : 0;
    int mt1 = half ? 25 : 13;

    int tid = threadIdx.x;
    int w = tid >> 6, l = tid & 63;
    int wr = w * 32;               // wave's 32 rows within the 128-row M-tile
    int l16 = l & 15, lc = l >> 4;

    // stage B strip: 64 rows x 32 chunks(16B). dest linear, source XOR'd.
#pragma unroll
    for (int it = 0; it < 8; ++it) {
        int idx = it * 256 + tid;
        int row = idx >> 5;
        int cd = idx & 31;
        int cs = cd ^ (row & 7);
        const unsigned short* g = B + (size_t)(n0 + row) * 256 + cs * 8;
        unsigned short* lp = &lB[(idx & ~63) * 8];   // wave-uniform base
        __builtin_amdgcn_global_load_lds((const GAS unsigned int*)g,
                                         (LAS unsigned int*)lp, 16, 0, 0);
    }

    // A fragments, single-buffered (overwritten WAR after each tile's MFMA)
    short8 af[2][8];
    auto loadA = [&](int mt) {
        const unsigned short* Abase =
            A + (size_t)(mt * 128 + wr + l16) * 256 + lc * 8;
#pragma unroll
        for (int i = 0; i < 2; ++i)
#pragma unroll
            for (int kt = 0; kt < 8; ++kt)
                af[i][kt] = *(const short8*)(Abase + (size_t)(i * 16) * 256 + kt * 32);
    };
    loadA(mt0);          // overlaps the staging
    __syncthreads();     // drains staging + first A (no stores pending yet)

    for (int mt = mt0; mt < mt1; ++mt) {
        f32x4 acc[2][4] = {};
#pragma unroll
        for (int kt = 0; kt < 8; ++kt) {
            short8 bf[4];
#pragma unroll
            for (int j = 0; j < 4; ++j) {
                int row = j * 16 + l16;
                int pc = (kt * 4 + lc) ^ (row & 7);
                bf[j] = *(const short8*)&lB[row * 256 + pc * 8];
            }
#pragma unroll
            for (int i = 0; i < 2; ++i)
#pragma unroll
                for (int j = 0; j < 4; ++j)
                    acc[i][j] = __builtin_amdgcn_mfma_f32_16x16x32_bf16(
                        af[i][kt], bf[j], acc[i][j], 0, 0, 0);
        }
        // prefetch next tile's A BEFORE the stores -> stores stay youngest
        if (mt + 1 < mt1) loadA(mt + 1);
        // stream out (normal cached stores; L2 assembles full lines)
#pragma unroll
        for (int i = 0; i < 2; ++i) {
            int mrow = mt * 128 + wr + i * 16 + lc * 4;
#pragma unroll
            for (int j = 0; j < 4; ++j) {
                int n = n0 + j * 16 + l16;
                if (n < V1) {
#pragma unroll
                    for (int rg = 0; rg < 4; ++rg)
                        out[(size_t)(mrow + rg) * V1 + n] = acc[i][j][rg];
                }
            }
        }
    }
}

// ---------------- driver ----------------

extern "C" void kernel_launch(void* const* d_in, const int* in_sizes, int n_in,
                              void* d_out, int out_size, void* d_ws, size_t ws_size,
                              hipStream_t stream) {
    const int*   ids      = (const int*)d_in[0];
    const float* item_emb = (const float*)d_in[1];
    const float* pos_emb  = (const float*)d_in[2];
    const float* emb_g    = (const float*)d_in[3];
    const float* emb_b    = (const float*)d_in[4];
    const float* Wv       = (const float*)d_in[5];
    const float* Wo       = (const float*)d_in[6];
    const float* attn_g   = (const float*)d_in[7];
    const float* attn_b   = (const float*)d_in[8];
    const float* W1       = (const float*)d_in[9];
    const float* b1       = (const float*)d_in[10];
    const float* W2       = (const float*)d_in[11];
    const float* b2       = (const float*)d_in[12];
    const float* ffn_g    = (const float*)d_in[13];
    const float* ffn_b    = (const float*)d_in[14];
    float* out = (float*)d_out;

    char* ws = (char*)d_ws;
    size_t off = 0;
    auto alloc = [&](size_t bytes) -> void* {
        void* p = ws + off;
        off += (bytes + 255) & ~(size_t)255;
        return p;
    };
    float* xf  = (float*)alloc((size_t)BL * H * 4);
    float* vbuf= (float*)alloc((size_t)BL * H * 4);
    float* y2  = (float*)alloc((size_t)BL * H * 4);
    unsigned short* xb  = (unsigned short*)alloc((size_t)BL * H * 2);
    unsigned short* y1b = (unsigned short*)alloc((size_t)BL * H * 2);
    unsigned short* WcB = (unsigned short*)alloc((size_t)2 * H * H * 2);
    unsigned short* W1B = (unsigned short*)alloc((size_t)2 * H * H * 2);
    unsigned short* W2B = (unsigned short*)alloc((size_t)2 * H * H * 2);
    unsigned short* WoB = (unsigned short*)alloc((size_t)2 * H * H * 2);
    unsigned short* WvT = (unsigned short*)alloc((size_t)2 * H * H * 2);
    unsigned short* embB= (unsigned short*)alloc((size_t)NPAD * H * 2);

    // --- prep ---
    k_f32_to_bf16<<<dim3(512), dim3(256), 0, stream>>>(W1, W1B, 2 * H * H);
    k_f32_to_bf16<<<dim3(512), dim3(256), 0, stream>>>(W2, W2B, 2 * H * H);
    k_f32_to_bf16<<<dim3(512), dim3(256), 0, stream>>>(Wo, WoB, 2 * H * H);
    k_transpose_bf<<<dim3(8, 8, 2), dim3(256), 0, stream>>>(Wv, WvT);
    {
        int n4 = NPAD * H / 4;
        k_conv_emb<<<dim3((n4 + 255) / 256), dim3(256), 0, stream>>>(item_emb, embB);
    }
    // Wc[i] = Wo[i] @ Wv[i]  via gemm64: A=WoB (o,m), B=WvT (h,m)
    for (int i = 0; i < 2; ++i)
        k_gemm64<0,0,0,1><<<dim3(4, 4), dim3(256), 0, stream>>>(
            WoB + (size_t)i * H * H, WvT + (size_t)i * H * H, nullptr,
            nullptr, WcB + (size_t)i * H * H, H, H);

    // --- embedding + LN ---
    k_embed_ln<<<dim3(BL), dim3(H), 0, stream>>>(ids, item_emb, pos_emb, emb_g, emb_b, xf, xb);

    // --- transformer blocks ---
    for (int i = 0; i < 2; ++i) {
        k_gemm64<0,0,1,0><<<dim3(BL / 64, H / 64), dim3(256), 0, stream>>>(
            xb, WcB + (size_t)i * H * H, nullptr, vbuf, nullptr, H, H);
        k_cumsum<<<dim3(NB, 4), dim3(64), 0, stream>>>(vbuf);
        k_add_ln<<<dim3(BL), dim3(H), 0, stream>>>(
            xf, vbuf, attn_g + (size_t)i * H, attn_b + (size_t)i * H, ids, xf, xb);
        k_gemm64<1,1,0,1><<<dim3(BL / 64, H / 64), dim3(256), 0, stream>>>(
            xb, W1B + (size_t)i * H * H, b1 + (size_t)i * H, nullptr, y1b, H, H);
        k_gemm64<1,0,1,0><<<dim3(BL / 64, H / 64), dim3(256), 0, stream>>>(
            y1b, W2B + (size_t)i * H * H, b2 + (size_t)i * H, y2, nullptr, H, H);
        k_add_ln<<<dim3(BL), dim3(H), 0, stream>>>(
            xf, y2, ffn_g + (size_t)i * H, ffn_b + (size_t)i * H, ids, xf, xb);
    }

    // --- logits = x @ item_emb^T ---
    k_logits<<<dim3(LGWG), dim3(256), 0, stream>>>(xb, embB, out);
}

// Round 8
// 549.214 us; speedup vs baseline: 1.6819x; 1.4335x over previous
//
#include <hip/hip_runtime.h>

#define H 256
#define LSEQ 200
#define NB 16
#define BL 3200           // NB * LSEQ
#define V1 50001
#define NPAD 50048        // V1 padded up to multiple of 64

#define GAS __attribute__((address_space(1)))
#define LAS __attribute__((address_space(3)))

typedef __attribute__((ext_vector_type(8))) short short8;
typedef __attribute__((ext_vector_type(4))) float f32x4;

__device__ __forceinline__ unsigned short f2bf(float f) {
    unsigned int u = __builtin_bit_cast(unsigned int, f);
    u += 0x7fffu + ((u >> 16) & 1u);   // round-to-nearest-even
    return (unsigned short)(u >> 16);
}

// ---------------- weight prep ----------------

__global__ void k_f32_to_bf16(const float* __restrict__ src,
                              unsigned short* __restrict__ dst, int n) {
    int i = blockIdx.x * blockDim.x + threadIdx.x;
    if (i < n) dst[i] = f2bf(src[i]);
}

// dst[i][h][m] = bf16(src[i][m][h])  -- 32x32 LDS tiles
__global__ __launch_bounds__(256) void k_transpose_bf(
    const float* __restrict__ src, unsigned short* __restrict__ dst) {
    __shared__ float t[32][33];
    int i = blockIdx.z;
    int m0 = blockIdx.x * 32, h0 = blockIdx.y * 32;
    int tx = threadIdx.x & 31, ty = threadIdx.x >> 5;   // 32 x 8
#pragma unroll
    for (int s = 0; s < 32; s += 8)
        t[ty + s][tx] = src[((size_t)i * 256 + m0 + ty + s) * 256 + h0 + tx];
    __syncthreads();
#pragma unroll
    for (int s = 0; s < 32; s += 8)
        dst[((size_t)i * 256 + h0 + ty + s) * 256 + m0 + tx] = f2bf(t[tx][ty + s]);
}

// item_emb f32 (V1 x H) -> bf16 (NPAD x H), pad rows zeroed. 4 elems/thread.
__global__ void k_conv_emb(const float* __restrict__ src, unsigned short* __restrict__ dst) {
    size_t i4 = (size_t)blockIdx.x * blockDim.x + threadIdx.x;
    size_t total4 = (size_t)NPAD * H / 4;
    if (i4 >= total4) return;
    size_t e0 = i4 * 4;
    size_t row = e0 >> 8;
    ushort4 o;
    if (row < V1) {
        float4 v = *(const float4*)(src + e0);
        o.x = f2bf(v.x); o.y = f2bf(v.y); o.z = f2bf(v.z); o.w = f2bf(v.w);
    } else {
        o.x = o.y = o.z = o.w = 0;
    }
    *(ushort4*)(dst + e0) = o;
}

// ---------------- LayerNorm kernels ----------------

__device__ __forceinline__ void block_reduce2(float& s, float& ss, float* red) {
#pragma unroll
    for (int off = 32; off > 0; off >>= 1) {
        s += __shfl_down(s, off);
        ss += __shfl_down(ss, off);
    }
    int t = threadIdx.x;
    if ((t & 63) == 0) { red[(t >> 6) * 2] = s; red[(t >> 6) * 2 + 1] = ss; }
    __syncthreads();
    s  = red[0] + red[2] + red[4] + red[6];
    ss = red[1] + red[3] + red[5] + red[7];
}

__global__ __launch_bounds__(256) void k_embed_ln(
    const int* __restrict__ ids, const float* __restrict__ emb,
    const float* __restrict__ pos, const float* __restrict__ g,
    const float* __restrict__ bta, float* __restrict__ xf,
    unsigned short* __restrict__ xb) {
    __shared__ float red[8];
    int bl = blockIdx.x;
    int h = threadIdx.x;
    int l = bl % LSEQ;
    int id = ids[bl];
    float val = emb[(size_t)id * H + h] * 16.0f + pos[(size_t)l * H + h];
    float s = val, ss = val * val;
    block_reduce2(s, ss, red);
    float mean = s * (1.0f / H);
    float var = fmaxf(ss * (1.0f / H) - mean * mean, 0.0f);
    float rs = rsqrtf(var + 1e-8f);
    float keep = (id != 0) ? 1.0f : 0.0f;
    float o = ((val - mean) * rs * g[h] + bta[h]) * keep;
    xf[(size_t)bl * H + h] = o;
    xb[(size_t)bl * H + h] = f2bf(o);
}

__global__ __launch_bounds__(256) void k_add_ln(
    const float* __restrict__ x, const float* __restrict__ d,
    const float* __restrict__ g, const float* __restrict__ bta,
    const int* __restrict__ ids, float* __restrict__ xf,
    unsigned short* __restrict__ xb) {
    __shared__ float red[8];
    int bl = blockIdx.x;
    int h = threadIdx.x;
    float val = x[(size_t)bl * H + h] + d[(size_t)bl * H + h];
    float s = val, ss = val * val;
    block_reduce2(s, ss, red);
    float mean = s * (1.0f / H);
    float var = fmaxf(ss * (1.0f / H) - mean * mean, 0.0f);
    float rs = rsqrtf(var + 1e-8f);
    float keep = (ids[bl] != 0) ? 1.0f : 0.0f;
    float o = ((val - mean) * rs * g[h] + bta[h]) * keep;
    xf[(size_t)bl * H + h] = o;
    xb[(size_t)bl * H + h] = f2bf(o);
}

// causal mean: in-place v[b,l,h] = (sum_{l'<=l} v[b,l',h]) / (l+1)
__global__ __launch_bounds__(64) void k_cumsum(float* __restrict__ v) {
    int b = blockIdx.x;
    int h = blockIdx.y * 64 + threadIdx.x;
    float* p = v + (size_t)b * LSEQ * H + h;
    float acc = 0.0f;
    for (int l = 0; l < LSEQ; l += 4) {
        float a0 = p[(size_t)(l + 0) * H];
        float a1 = p[(size_t)(l + 1) * H];
        float a2 = p[(size_t)(l + 2) * H];
        float a3 = p[(size_t)(l + 3) * H];
        acc += a0; p[(size_t)(l + 0) * H] = acc * (1.0f / (float)(l + 1));
        acc += a1; p[(size_t)(l + 1) * H] = acc * (1.0f / (float)(l + 2));
        acc += a2; p[(size_t)(l + 2) * H] = acc * (1.0f / (float)(l + 3));
        acc += a3; p[(size_t)(l + 3) * H] = acc * (1.0f / (float)(l + 4));
    }
}

// ---------------- small MFMA GEMM (H x H weights) ----------------
template<int BIAS, int RELU, int WF32, int WBF16>
__global__ __launch_bounds__(256) void k_gemm64(
    const unsigned short* __restrict__ A,
    const unsigned short* __restrict__ Bmat,
    const float* __restrict__ bias,
    float* __restrict__ outF,
    unsigned short* __restrict__ outB,
    int N, int K) {
    int bm = blockIdx.x * 64;
    int bn = blockIdx.y * 64;
    int tid = threadIdx.x;
    int w = tid >> 6, l = tid & 63;
    int wr = (w >> 1) * 32, wc = (w & 1) * 32;
    int l16 = l & 15, lk = (l >> 4) * 8;

    const unsigned short* Ap = A + (size_t)(bm + wr + l16) * K + lk;
    const unsigned short* Bp = Bmat + (size_t)(bn + wc + l16) * K + lk;

    f32x4 acc00 = {0.f,0.f,0.f,0.f}, acc01 = {0.f,0.f,0.f,0.f};
    f32x4 acc10 = {0.f,0.f,0.f,0.f}, acc11 = {0.f,0.f,0.f,0.f};

#pragma unroll
    for (int k0 = 0; k0 < 256; k0 += 32) {
        short8 a0 = *(const short8*)(Ap + k0);
        short8 a1 = *(const short8*)(Ap + (size_t)16 * K + k0);
        short8 b0 = *(const short8*)(Bp + k0);
        short8 b1 = *(const short8*)(Bp + (size_t)16 * K + k0);
        acc00 = __builtin_amdgcn_mfma_f32_16x16x32_bf16(a0, b0, acc00, 0, 0, 0);
        acc01 = __builtin_amdgcn_mfma_f32_16x16x32_bf16(a0, b1, acc01, 0, 0, 0);
        acc10 = __builtin_amdgcn_mfma_f32_16x16x32_bf16(a1, b0, acc10, 0, 0, 0);
        acc11 = __builtin_amdgcn_mfma_f32_16x16x32_bf16(a1, b1, acc11, 0, 0, 0);
    }

    int r0 = (l >> 4) * 4;
#pragma unroll
    for (int i = 0; i < 2; ++i) {
#pragma unroll
        for (int j = 0; j < 2; ++j) {
            f32x4 a = (i == 0) ? (j == 0 ? acc00 : acc01) : (j == 0 ? acc10 : acc11);
            int col = bn + wc + j * 16 + l16;
            float bv = BIAS ? bias[col] : 0.0f;
            int rowb = bm + wr + i * 16 + r0;
#pragma unroll
            for (int r = 0; r < 4; ++r) {
                float vv = a[r] + bv;
                if (RELU) vv = fmaxf(vv, 0.0f);
                size_t idx = (size_t)(rowb + r) * N + col;
                if (WF32) outF[idx] = vv;
                if (WBF16) outB[idx] = f2bf(vv);
            }
        }
    }
}

// ---------------- logits GEMM: streaming-store N-strips, A dbuf ----------------
// 32-col strip per block, B in regs (persistent). A fragments DOUBLE-buffered
// (afA/afB, statically named; 2-tile unrolled loop): tile t+1's loads are
// issued at the TOP of the iteration, so the vmcnt wait before tile t+1's
// MFMA targets loads issued a full iteration earlier -> latency hidden.
// Stores remain the youngest vmem ops -> never drained by the counted wait.
// No LDS, no barriers.
#define LGSTRIPS 1564                // NPAD / 32
#define LGWG (LGSTRIPS * 2)          // 3128, M split in halves (13 + 12 tiles)

#define COMPUTE_STORE(MT, AF)                                               \
    {                                                                       \
        f32x4 acc[2][2] = {};                                               \
        _Pragma("unroll")                                                   \
        for (int kt = 0; kt < 8; ++kt)                                      \
            _Pragma("unroll")                                               \
            for (int i = 0; i < 2; ++i)                                     \
                _Pragma("unroll")                                           \
                for (int j = 0; j < 2; ++j)                                 \
                    acc[i][j] = __builtin_amdgcn_mfma_f32_16x16x32_bf16(    \
                        AF[i][kt], breg[j][kt], acc[i][j], 0, 0, 0);        \
        _Pragma("unroll")                                                   \
        for (int i = 0; i < 2; ++i) {                                       \
            int mrow = (MT) * 128 + wr + i * 16 + lc * 4;                   \
            _Pragma("unroll")                                               \
            for (int j = 0; j < 2; ++j) {                                   \
                int n = n0 + j * 16 + l16;                                  \
                if (n < V1) {                                               \
                    _Pragma("unroll")                                       \
                    for (int rg = 0; rg < 4; ++rg)                          \
                        out[(size_t)(mrow + rg) * V1 + n] = acc[i][j][rg];  \
                }                                                           \
            }                                                               \
        }                                                                   \
    }

__global__ __launch_bounds__(256, 2) void k_logits(
    const unsigned short* __restrict__ A,   // BL x 256 bf16
    const unsigned short* __restrict__ B,   // NPAD x 256 bf16
    float* __restrict__ out) {              // BL x V1 f32
    int bid = blockIdx.x;
    int strip = bid >> 1, half = bid & 1;
    int n0 = strip * 32;
    int mt0 = half ? 13 : 0;
    int mt1 = half ? 25 : 13;

    int tid = threadIdx.x;
    int w = tid >> 6, l = tid & 63;
    int wr = w * 32;               // wave's 32 rows within the 128-row tile
    int l16 = l & 15, lc = l >> 4;

    // B strip -> registers (persistent): rows n0 + j*16 + l16
    short8 breg[2][8];
#pragma unroll
    for (int j = 0; j < 2; ++j)
#pragma unroll
        for (int kt = 0; kt < 8; ++kt)
            breg[j][kt] = *(const short8*)(
                B + (size_t)(n0 + j * 16 + l16) * 256 + kt * 32 + lc * 8);

    // A fragments, DOUBLE-buffered (statically named)
    short8 afA[2][8], afB[2][8];
    auto loadA = [&](int mt, short8 dst[2][8]) {
        const unsigned short* Abase =
            A + (size_t)(mt * 128 + wr + l16) * 256 + lc * 8;
#pragma unroll
        for (int i = 0; i < 2; ++i)
#pragma unroll
            for (int kt = 0; kt < 8; ++kt)
                dst[i][kt] = *(const short8*)(Abase + (size_t)(i * 16) * 256 + kt * 32);
    };

    loadA(mt0, afA);
    int mt = mt0;
    for (; mt + 2 <= mt1; mt += 2) {
        loadA(mt + 1, afB);            // issue next tile's loads FIRST
        COMPUTE_STORE(mt, afA);        // waits on loads issued last iteration
        if (mt + 2 < mt1) loadA(mt + 2, afA);
        COMPUTE_STORE(mt + 1, afB);
    }
    if (mt < mt1) COMPUTE_STORE(mt, afA);   // odd tail (afA already loaded)
}

// ---------------- driver ----------------

extern "C" void kernel_launch(void* const* d_in, const int* in_sizes, int n_in,
                              void* d_out, int out_size, void* d_ws, size_t ws_size,
                              hipStream_t stream) {
    const int*   ids      = (const int*)d_in[0];
    const float* item_emb = (const float*)d_in[1];
    const float* pos_emb  = (const float*)d_in[2];
    const float* emb_g    = (const float*)d_in[3];
    const float* emb_b    = (const float*)d_in[4];
    const float* Wv       = (const float*)d_in[5];
    const float* Wo       = (const float*)d_in[6];
    const float* attn_g   = (const float*)d_in[7];
    const float* attn_b   = (const float*)d_in[8];
    const float* W1       = (const float*)d_in[9];
    const float* b1       = (const float*)d_in[10];
    const float* W2       = (const float*)d_in[11];
    const float* b2       = (const float*)d_in[12];
    const float* ffn_g    = (const float*)d_in[13];
    const float* ffn_b    = (const float*)d_in[14];
    float* out = (float*)d_out;

    char* ws = (char*)d_ws;
    size_t off = 0;
    auto alloc = [&](size_t bytes) -> void* {
        void* p = ws + off;
        off += (bytes + 255) & ~(size_t)255;
        return p;
    };
    float* xf  = (float*)alloc((size_t)BL * H * 4);
    float* vbuf= (float*)alloc((size_t)BL * H * 4);
    float* y2  = (float*)alloc((size_t)BL * H * 4);
    unsigned short* xb  = (unsigned short*)alloc((size_t)BL * H * 2);
    unsigned short* y1b = (unsigned short*)alloc((size_t)BL * H * 2);
    unsigned short* WcB = (unsigned short*)alloc((size_t)2 * H * H * 2);
    unsigned short* W1B = (unsigned short*)alloc((size_t)2 * H * H * 2);
    unsigned short* W2B = (unsigned short*)alloc((size_t)2 * H * H * 2);
    unsigned short* WoB = (unsigned short*)alloc((size_t)2 * H * H * 2);
    unsigned short* WvT = (unsigned short*)alloc((size_t)2 * H * H * 2);
    unsigned short* embB= (unsigned short*)alloc((size_t)NPAD * H * 2);

    // --- prep ---
    k_f32_to_bf16<<<dim3(512), dim3(256), 0, stream>>>(W1, W1B, 2 * H * H);
    k_f32_to_bf16<<<dim3(512), dim3(256), 0, stream>>>(W2, W2B, 2 * H * H);
    k_f32_to_bf16<<<dim3(512), dim3(256), 0, stream>>>(Wo, WoB, 2 * H * H);
    k_transpose_bf<<<dim3(8, 8, 2), dim3(256), 0, stream>>>(Wv, WvT);
    {
        int n4 = NPAD * H / 4;
        k_conv_emb<<<dim3((n4 + 255) / 256), dim3(256), 0, stream>>>(item_emb, embB);
    }
    // Wc[i] = Wo[i] @ Wv[i]  via gemm64: A=WoB (o,m), B=WvT (h,m)
    for (int i = 0; i < 2; ++i)
        k_gemm64<0,0,0,1><<<dim3(4, 4), dim3(256), 0, stream>>>(
            WoB + (size_t)i * H * H, WvT + (size_t)i * H * H, nullptr,
            nullptr, WcB + (size_t)i * H * H, H, H);

    // --- embedding + LN ---
    k_embed_ln<<<dim3(BL), dim3(H), 0, stream>>>(ids, item_emb, pos_emb, emb_g, emb_b, xf, xb);

    // --- transformer blocks ---
    for (int i = 0; i < 2; ++i) {
        k_gemm64<0,0,1,0><<<dim3(BL / 64, H / 64), dim3(256), 0, stream>>>(
            xb, WcB + (size_t)i * H * H, nullptr, vbuf, nullptr, H, H);
        k_cumsum<<<dim3(NB, 4), dim3(64), 0, stream>>>(vbuf);
        k_add_ln<<<dim3(BL), dim3(H), 0, stream>>>(
            xf, vbuf, attn_g + (size_t)i * H, attn_b + (size_t)i * H, ids, xf, xb);
        k_gemm64<1,1,0,1><<<dim3(BL / 64, H / 64), dim3(256), 0, stream>>>(
            xb, W1B + (size_t)i * H * H, b1 + (size_t)i * H, nullptr, y1b, H, H);
        k_gemm64<1,0,1,0><<<dim3(BL / 64, H / 64), dim3(256), 0, stream>>>(
            y1b, W2B + (size_t)i * H * H, b2 + (size_t)i * H, y2, nullptr, H, H);
        k_add_ln<<<dim3(BL), dim3(H), 0, stream>>>(
            xf, y2, ffn_g + (size_t)i * H, ffn_b + (size_t)i * H, ids, xf, xb);
    }

    // --- logits = x @ item_emb^T ---
    k_logits<<<dim3(LGWG), dim3(256), 0, stream>>>(xb, embB, out);
}

// Round 9
// 449.372 us; speedup vs baseline: 2.0556x; 1.2222x over previous
//
#include <hip/hip_runtime.h>

#define H 256
#define LSEQ 200
#define NB 16
#define BL 3200           // NB * LSEQ
#define V1 50001
#define NPAD 50048        // V1 padded up to multiple of 64

#define GAS __attribute__((address_space(1)))
#define LAS __attribute__((address_space(3)))

typedef __attribute__((ext_vector_type(8))) short short8;
typedef __attribute__((ext_vector_type(4))) float f32x4;

__device__ __forceinline__ unsigned short f2bf(float f) {
    unsigned int u = __builtin_bit_cast(unsigned int, f);
    u += 0x7fffu + ((u >> 16) & 1u);   // round-to-nearest-even
    return (unsigned short)(u >> 16);
}

// ---------------- weight prep ----------------

__global__ void k_f32_to_bf16(const float* __restrict__ src,
                              unsigned short* __restrict__ dst, int n) {
    int i = blockIdx.x * blockDim.x + threadIdx.x;
    if (i < n) dst[i] = f2bf(src[i]);
}

// dst[i][h][m] = bf16(src[i][m][h])  -- 32x32 LDS tiles
__global__ __launch_bounds__(256) void k_transpose_bf(
    const float* __restrict__ src, unsigned short* __restrict__ dst) {
    __shared__ float t[32][33];
    int i = blockIdx.z;
    int m0 = blockIdx.x * 32, h0 = blockIdx.y * 32;
    int tx = threadIdx.x & 31, ty = threadIdx.x >> 5;   // 32 x 8
#pragma unroll
    for (int s = 0; s < 32; s += 8)
        t[ty + s][tx] = src[((size_t)i * 256 + m0 + ty + s) * 256 + h0 + tx];
    __syncthreads();
#pragma unroll
    for (int s = 0; s < 32; s += 8)
        dst[((size_t)i * 256 + h0 + ty + s) * 256 + m0 + tx] = f2bf(t[tx][ty + s]);
}

// item_emb f32 (V1 x H) -> bf16 (NPAD x H), pad rows zeroed. 4 elems/thread.
__global__ void k_conv_emb(const float* __restrict__ src, unsigned short* __restrict__ dst) {
    size_t i4 = (size_t)blockIdx.x * blockDim.x + threadIdx.x;
    size_t total4 = (size_t)NPAD * H / 4;
    if (i4 >= total4) return;
    size_t e0 = i4 * 4;
    size_t row = e0 >> 8;
    ushort4 o;
    if (row < V1) {
        float4 v = *(const float4*)(src + e0);
        o.x = f2bf(v.x); o.y = f2bf(v.y); o.z = f2bf(v.z); o.w = f2bf(v.w);
    } else {
        o.x = o.y = o.z = o.w = 0;
    }
    *(ushort4*)(dst + e0) = o;
}

// ---------------- LayerNorm kernels ----------------

__device__ __forceinline__ void block_reduce2(float& s, float& ss, float* red) {
#pragma unroll
    for (int off = 32; off > 0; off >>= 1) {
        s += __shfl_down(s, off);
        ss += __shfl_down(ss, off);
    }
    int t = threadIdx.x;
    if ((t & 63) == 0) { red[(t >> 6) * 2] = s; red[(t >> 6) * 2 + 1] = ss; }
    __syncthreads();
    s  = red[0] + red[2] + red[4] + red[6];
    ss = red[1] + red[3] + red[5] + red[7];
}

__global__ __launch_bounds__(256) void k_embed_ln(
    const int* __restrict__ ids, const float* __restrict__ emb,
    const float* __restrict__ pos, const float* __restrict__ g,
    const float* __restrict__ bta, float* __restrict__ xf,
    unsigned short* __restrict__ xb) {
    __shared__ float red[8];
    int bl = blockIdx.x;
    int h = threadIdx.x;
    int l = bl % LSEQ;
    int id = ids[bl];
    float val = emb[(size_t)id * H + h] * 16.0f + pos[(size_t)l * H + h];
    float s = val, ss = val * val;
    block_reduce2(s, ss, red);
    float mean = s * (1.0f / H);
    float var = fmaxf(ss * (1.0f / H) - mean * mean, 0.0f);
    float rs = rsqrtf(var + 1e-8f);
    float keep = (id != 0) ? 1.0f : 0.0f;
    float o = ((val - mean) * rs * g[h] + bta[h]) * keep;
    xf[(size_t)bl * H + h] = o;
    xb[(size_t)bl * H + h] = f2bf(o);
}

__global__ __launch_bounds__(256) void k_add_ln(
    const float* __restrict__ x, const float* __restrict__ d,
    const float* __restrict__ g, const float* __restrict__ bta,
    const int* __restrict__ ids, float* __restrict__ xf,
    unsigned short* __restrict__ xb) {
    __shared__ float red[8];
    int bl = blockIdx.x;
    int h = threadIdx.x;
    float val = x[(size_t)bl * H + h] + d[(size_t)bl * H + h];
    float s = val, ss = val * val;
    block_reduce2(s, ss, red);
    float mean = s * (1.0f / H);
    float var = fmaxf(ss * (1.0f / H) - mean * mean, 0.0f);
    float rs = rsqrtf(var + 1e-8f);
    float keep = (ids[bl] != 0) ? 1.0f : 0.0f;
    float o = ((val - mean) * rs * g[h] + bta[h]) * keep;
    xf[(size_t)bl * H + h] = o;
    xb[(size_t)bl * H + h] = f2bf(o);
}

// causal mean: in-place v[b,l,h] = (sum_{l'<=l} v[b,l',h]) / (l+1)
__global__ __launch_bounds__(64) void k_cumsum(float* __restrict__ v) {
    int b = blockIdx.x;
    int h = blockIdx.y * 64 + threadIdx.x;
    float* p = v + (size_t)b * LSEQ * H + h;
    float acc = 0.0f;
    for (int l = 0; l < LSEQ; l += 4) {
        float a0 = p[(size_t)(l + 0) * H];
        float a1 = p[(size_t)(l + 1) * H];
        float a2 = p[(size_t)(l + 2) * H];
        float a3 = p[(size_t)(l + 3) * H];
        acc += a0; p[(size_t)(l + 0) * H] = acc * (1.0f / (float)(l + 1));
        acc += a1; p[(size_t)(l + 1) * H] = acc * (1.0f / (float)(l + 2));
        acc += a2; p[(size_t)(l + 2) * H] = acc * (1.0f / (float)(l + 3));
        acc += a3; p[(size_t)(l + 3) * H] = acc * (1.0f / (float)(l + 4));
    }
}

// ---------------- small MFMA GEMM (H x H weights) ----------------
template<int BIAS, int RELU, int WF32, int WBF16>
__global__ __launch_bounds__(256) void k_gemm64(
    const unsigned short* __restrict__ A,
    const unsigned short* __restrict__ Bmat,
    const float* __restrict__ bias,
    float* __restrict__ outF,
    unsigned short* __restrict__ outB,
    int N, int K) {
    int bm = blockIdx.x * 64;
    int bn = blockIdx.y * 64;
    int tid = threadIdx.x;
    int w = tid >> 6, l = tid & 63;
    int wr = (w >> 1) * 32, wc = (w & 1) * 32;
    int l16 = l & 15, lk = (l >> 4) * 8;

    const unsigned short* Ap = A + (size_t)(bm + wr + l16) * K + lk;
    const unsigned short* Bp = Bmat + (size_t)(bn + wc + l16) * K + lk;

    f32x4 acc00 = {0.f,0.f,0.f,0.f}, acc01 = {0.f,0.f,0.f,0.f};
    f32x4 acc10 = {0.f,0.f,0.f,0.f}, acc11 = {0.f,0.f,0.f,0.f};

#pragma unroll
    for (int k0 = 0; k0 < 256; k0 += 32) {
        short8 a0 = *(const short8*)(Ap + k0);
        short8 a1 = *(const short8*)(Ap + (size_t)16 * K + k0);
        short8 b0 = *(const short8*)(Bp + k0);
        short8 b1 = *(const short8*)(Bp + (size_t)16 * K + k0);
        acc00 = __builtin_amdgcn_mfma_f32_16x16x32_bf16(a0, b0, acc00, 0, 0, 0);
        acc01 = __builtin_amdgcn_mfma_f32_16x16x32_bf16(a0, b1, acc01, 0, 0, 0);
        acc10 = __builtin_amdgcn_mfma_f32_16x16x32_bf16(a1, b0, acc10, 0, 0, 0);
        acc11 = __builtin_amdgcn_mfma_f32_16x16x32_bf16(a1, b1, acc11, 0, 0, 0);
    }

    int r0 = (l >> 4) * 4;
#pragma unroll
    for (int i = 0; i < 2; ++i) {
#pragma unroll
        for (int j = 0; j < 2; ++j) {
            f32x4 a = (i == 0) ? (j == 0 ? acc00 : acc01) : (j == 0 ? acc10 : acc11);
            int col = bn + wc + j * 16 + l16;
            float bv = BIAS ? bias[col] : 0.0f;
            int rowb = bm + wr + i * 16 + r0;
#pragma unroll
            for (int r = 0; r < 4; ++r) {
                float vv = a[r] + bv;
                if (RELU) vv = fmaxf(vv, 0.0f);
                size_t idx = (size_t)(rowb + r) * N + col;
                if (WF32) outF[idx] = vv;
                if (WBF16) outB[idx] = f2bf(vv);
            }
        }
    }
}

// ---------------- logits GEMM: one 128x64 tile per block ----------------
// Structure chosen to kill the measured killers:
//  - stores ONLY in the epilogue (no per-tile acc WAR -> no store-drain
//    stalls inside any loop; drain overlaps the next resident block),
//  - B staged once to LDS (32KB, chunk-XOR swizzle, one barrier/block),
//  - A tile straight to VGPRs (64/lane), K=256 fully unrolled, 64 MFMA/wave,
//  - 3 blocks/CU resident; M-fast + bijective XCD swizzle for B-tile reuse.
#define LGM 25                       // 3200 / 128
#define LGN 782                      // NPAD / 64
#define LGWG (LGM * LGN)             // 19550

__global__ __launch_bounds__(256, 3) void k_logits(
    const unsigned short* __restrict__ A,   // BL x 256 bf16
    const unsigned short* __restrict__ B,   // NPAD x 256 bf16
    float* __restrict__ out) {              // BL x V1 f32
    __shared__ unsigned short lB[64 * 256];  // 32KB

    // bijective XCD swizzle over 19550 workgroups (19550 = 8*2443 + 6)
    int orig = blockIdx.x;
    int q = LGWG >> 3, r = LGWG & 7;
    int xcd = orig & 7, sub = orig >> 3;
    int wg = (xcd < r ? xcd * (q + 1) : r * (q + 1) + (xcd - r) * q) + sub;
    int mi = wg % LGM, ni = wg / LGM;    // M fast -> consecutive wgs share B tile
    int bm = mi * 128, n0 = ni * 64;

    int tid = threadIdx.x;
    int w = tid >> 6, l = tid & 63;
    int wr = w * 32;                     // wave's 32 rows of the 128-row tile
    int l16 = l & 15, lc = l >> 4;

    // stage B tile: 64 rows x 32 chunks(16B). dest linear, source chunk-XOR'd.
#pragma unroll
    for (int it = 0; it < 8; ++it) {
        int idx = it * 256 + tid;
        int row = idx >> 5;
        int cd = idx & 31;
        int cs = cd ^ (row & 7);
        const unsigned short* g = B + (size_t)(n0 + row) * 256 + cs * 8;
        unsigned short* lp = &lB[(idx & ~63) * 8];   // wave-uniform base
        __builtin_amdgcn_global_load_lds((const GAS unsigned int*)g,
                                         (LAS unsigned int*)lp, 16, 0, 0);
    }

    // A tile -> VGPRs (overlaps B staging; both drained by the one barrier)
    short8 af[2][8];
    {
        const unsigned short* Abase = A + (size_t)(bm + wr + l16) * 256 + lc * 8;
#pragma unroll
        for (int i = 0; i < 2; ++i)
#pragma unroll
            for (int kt = 0; kt < 8; ++kt)
                af[i][kt] = *(const short8*)(Abase + (size_t)(i * 16) * 256 + kt * 32);
    }
    __syncthreads();   // the ONLY barrier: no stores exist yet, nothing re-drained

    f32x4 acc[2][4] = {};
#pragma unroll
    for (int kt = 0; kt < 8; ++kt) {
        short8 bf[4];
#pragma unroll
        for (int j = 0; j < 4; ++j) {
            int row = j * 16 + l16;
            int pc = (kt * 4 + lc) ^ (row & 7);
            bf[j] = *(const short8*)&lB[row * 256 + pc * 8];
        }
#pragma unroll
        for (int i = 0; i < 2; ++i)
#pragma unroll
            for (int j = 0; j < 4; ++j)
                acc[i][j] = __builtin_amdgcn_mfma_f32_16x16x32_bf16(
                    af[i][kt], bf[j], acc[i][j], 0, 0, 0);
    }

    // epilogue: the block's only stores; wave exits right after, drain
    // overlaps the next block's stage/compute.
#pragma unroll
    for (int i = 0; i < 2; ++i) {
        int mrow = bm + wr + i * 16 + lc * 4;
#pragma unroll
        for (int j = 0; j < 4; ++j) {
            int n = n0 + j * 16 + l16;
            if (n < V1) {
#pragma unroll
                for (int rg = 0; rg < 4; ++rg)
                    out[(size_t)(mrow + rg) * V1 + n] = acc[i][j][rg];
            }
        }
    }
}

// ---------------- driver ----------------

extern "C" void kernel_launch(void* const* d_in, const int* in_sizes, int n_in,
                              void* d_out, int out_size, void* d_ws, size_t ws_size,
                              hipStream_t stream) {
    const int*   ids      = (const int*)d_in[0];
    const float* item_emb = (const float*)d_in[1];
    const float* pos_emb  = (const float*)d_in[2];
    const float* emb_g    = (const float*)d_in[3];
    const float* emb_b    = (const float*)d_in[4];
    const float* Wv       = (const float*)d_in[5];
    const float* Wo       = (const float*)d_in[6];
    const float* attn_g   = (const float*)d_in[7];
    const float* attn_b   = (const float*)d_in[8];
    const float* W1       = (const float*)d_in[9];
    const float* b1       = (const float*)d_in[10];
    const float* W2       = (const float*)d_in[11];
    const float* b2       = (const float*)d_in[12];
    const float* ffn_g    = (const float*)d_in[13];
    const float* ffn_b    = (const float*)d_in[14];
    float* out = (float*)d_out;

    char* ws = (char*)d_ws;
    size_t off = 0;
    auto alloc = [&](size_t bytes) -> void* {
        void* p = ws + off;
        off += (bytes + 255) & ~(size_t)255;
        return p;
    };
    float* xf  = (float*)alloc((size_t)BL * H * 4);
    float* vbuf= (float*)alloc((size_t)BL * H * 4);
    float* y2  = (float*)alloc((size_t)BL * H * 4);
    unsigned short* xb  = (unsigned short*)alloc((size_t)BL * H * 2);
    unsigned short* y1b = (unsigned short*)alloc((size_t)BL * H * 2);
    unsigned short* WcB = (unsigned short*)alloc((size_t)2 * H * H * 2);
    unsigned short* W1B = (unsigned short*)alloc((size_t)2 * H * H * 2);
    unsigned short* W2B = (unsigned short*)alloc((size_t)2 * H * H * 2);
    unsigned short* WoB = (unsigned short*)alloc((size_t)2 * H * H * 2);
    unsigned short* WvT = (unsigned short*)alloc((size_t)2 * H * H * 2);
    unsigned short* embB= (unsigned short*)alloc((size_t)NPAD * H * 2);

    // --- prep ---
    k_f32_to_bf16<<<dim3(512), dim3(256), 0, stream>>>(W1, W1B, 2 * H * H);
    k_f32_to_bf16<<<dim3(512), dim3(256), 0, stream>>>(W2, W2B, 2 * H * H);
    k_f32_to_bf16<<<dim3(512), dim3(256), 0, stream>>>(Wo, WoB, 2 * H * H);
    k_transpose_bf<<<dim3(8, 8, 2), dim3(256), 0, stream>>>(Wv, WvT);
    {
        int n4 = NPAD * H / 4;
        k_conv_emb<<<dim3((n4 + 255) / 256), dim3(256), 0, stream>>>(item_emb, embB);
    }
    // Wc[i] = Wo[i] @ Wv[i]  via gemm64: A=WoB (o,m), B=WvT (h,m)
    for (int i = 0; i < 2; ++i)
        k_gemm64<0,0,0,1><<<dim3(4, 4), dim3(256), 0, stream>>>(
            WoB + (size_t)i * H * H, WvT + (size_t)i * H * H, nullptr,
            nullptr, WcB + (size_t)i * H * H, H, H);

    // --- embedding + LN ---
    k_embed_ln<<<dim3(BL), dim3(H), 0, stream>>>(ids, item_emb, pos_emb, emb_g, emb_b, xf, xb);

    // --- transformer blocks ---
    for (int i = 0; i < 2; ++i) {
        k_gemm64<0,0,1,0><<<dim3(BL / 64, H / 64), dim3(256), 0, stream>>>(
            xb, WcB + (size_t)i * H * H, nullptr, vbuf, nullptr, H, H);
        k_cumsum<<<dim3(NB, 4), dim3(64), 0, stream>>>(vbuf);
        k_add_ln<<<dim3(BL), dim3(H), 0, stream>>>(
            xf, vbuf, attn_g + (size_t)i * H, attn_b + (size_t)i * H, ids, xf, xb);
        k_gemm64<1,1,0,1><<<dim3(BL / 64, H / 64), dim3(256), 0, stream>>>(
            xb, W1B + (size_t)i * H * H, b1 + (size_t)i * H, nullptr, y1b, H, H);
        k_gemm64<1,0,1,0><<<dim3(BL / 64, H / 64), dim3(256), 0, stream>>>(
            y1b, W2B + (size_t)i * H * H, b2 + (size_t)i * H, y2, nullptr, H, H);
        k_add_ln<<<dim3(BL), dim3(H), 0, stream>>>(
            xf, y2, ffn_g + (size_t)i * H, ffn_b + (size_t)i * H, ids, xf, xb);
    }

    // --- logits = x @ item_emb^T ---
    k_logits<<<dim3(LGWG), dim3(256), 0, stream>>>(xb, embB, out);
}

// Round 10
// 441.156 us; speedup vs baseline: 2.0939x; 1.0186x over previous
//
#include <hip/hip_runtime.h>

#define H 256
#define LSEQ 200
#define NB 16
#define BL 3200           // NB * LSEQ
#define V1 50001
#define NPAD 50048        // V1 padded up to multiple of 64

#define GAS __attribute__((address_space(1)))
#define LAS __attribute__((address_space(3)))

typedef __attribute__((ext_vector_type(8))) short short8;
typedef __attribute__((ext_vector_type(4))) float f32x4;

__device__ __forceinline__ unsigned short f2bf(float f) {
    unsigned int u = __builtin_bit_cast(unsigned int, f);
    u += 0x7fffu + ((u >> 16) & 1u);   // round-to-nearest-even
    return (unsigned short)(u >> 16);
}

// ---------------- weight prep ----------------

__global__ void k_f32_to_bf16(const float* __restrict__ src,
                              unsigned short* __restrict__ dst, int n) {
    int i = blockIdx.x * blockDim.x + threadIdx.x;
    if (i < n) dst[i] = f2bf(src[i]);
}

// dst[i][h][m] = bf16(src[i][m][h])  -- 32x32 LDS tiles
__global__ __launch_bounds__(256) void k_transpose_bf(
    const float* __restrict__ src, unsigned short* __restrict__ dst) {
    __shared__ float t[32][33];
    int i = blockIdx.z;
    int m0 = blockIdx.x * 32, h0 = blockIdx.y * 32;
    int tx = threadIdx.x & 31, ty = threadIdx.x >> 5;   // 32 x 8
#pragma unroll
    for (int s = 0; s < 32; s += 8)
        t[ty + s][tx] = src[((size_t)i * 256 + m0 + ty + s) * 256 + h0 + tx];
    __syncthreads();
#pragma unroll
    for (int s = 0; s < 32; s += 8)
        dst[((size_t)i * 256 + h0 + ty + s) * 256 + m0 + tx] = f2bf(t[tx][ty + s]);
}

// item_emb f32 (V1 x H) -> bf16 (NPAD x H), pad rows zeroed. 4 elems/thread.
__global__ void k_conv_emb(const float* __restrict__ src, unsigned short* __restrict__ dst) {
    size_t i4 = (size_t)blockIdx.x * blockDim.x + threadIdx.x;
    size_t total4 = (size_t)NPAD * H / 4;
    if (i4 >= total4) return;
    size_t e0 = i4 * 4;
    size_t row = e0 >> 8;
    ushort4 o;
    if (row < V1) {
        float4 v = *(const float4*)(src + e0);
        o.x = f2bf(v.x); o.y = f2bf(v.y); o.z = f2bf(v.z); o.w = f2bf(v.w);
    } else {
        o.x = o.y = o.z = o.w = 0;
    }
    *(ushort4*)(dst + e0) = o;
}

// ---------------- LayerNorm kernels ----------------

__device__ __forceinline__ void block_reduce2(float& s, float& ss, float* red) {
#pragma unroll
    for (int off = 32; off > 0; off >>= 1) {
        s += __shfl_down(s, off);
        ss += __shfl_down(ss, off);
    }
    int t = threadIdx.x;
    if ((t & 63) == 0) { red[(t >> 6) * 2] = s; red[(t >> 6) * 2 + 1] = ss; }
    __syncthreads();
    s  = red[0] + red[2] + red[4] + red[6];
    ss = red[1] + red[3] + red[5] + red[7];
}

__global__ __launch_bounds__(256) void k_embed_ln(
    const int* __restrict__ ids, const float* __restrict__ emb,
    const float* __restrict__ pos, const float* __restrict__ g,
    const float* __restrict__ bta, float* __restrict__ xf,
    unsigned short* __restrict__ xb) {
    __shared__ float red[8];
    int bl = blockIdx.x;
    int h = threadIdx.x;
    int l = bl % LSEQ;
    int id = ids[bl];
    float val = emb[(size_t)id * H + h] * 16.0f + pos[(size_t)l * H + h];
    float s = val, ss = val * val;
    block_reduce2(s, ss, red);
    float mean = s * (1.0f / H);
    float var = fmaxf(ss * (1.0f / H) - mean * mean, 0.0f);
    float rs = rsqrtf(var + 1e-8f);
    float keep = (id != 0) ? 1.0f : 0.0f;
    float o = ((val - mean) * rs * g[h] + bta[h]) * keep;
    xf[(size_t)bl * H + h] = o;
    xb[(size_t)bl * H + h] = f2bf(o);
}

__global__ __launch_bounds__(256) void k_add_ln(
    const float* __restrict__ x, const float* __restrict__ d,
    const float* __restrict__ g, const float* __restrict__ bta,
    const int* __restrict__ ids, float* __restrict__ xf,
    unsigned short* __restrict__ xb) {
    __shared__ float red[8];
    int bl = blockIdx.x;
    int h = threadIdx.x;
    float val = x[(size_t)bl * H + h] + d[(size_t)bl * H + h];
    float s = val, ss = val * val;
    block_reduce2(s, ss, red);
    float mean = s * (1.0f / H);
    float var = fmaxf(ss * (1.0f / H) - mean * mean, 0.0f);
    float rs = rsqrtf(var + 1e-8f);
    float keep = (ids[bl] != 0) ? 1.0f : 0.0f;
    float o = ((val - mean) * rs * g[h] + bta[h]) * keep;
    xf[(size_t)bl * H + h] = o;
    xb[(size_t)bl * H + h] = f2bf(o);
}

// causal mean: in-place v[b,l,h] = (sum_{l'<=l} v[b,l',h]) / (l+1)
__global__ __launch_bounds__(64) void k_cumsum(float* __restrict__ v) {
    int b = blockIdx.x;
    int h = blockIdx.y * 64 + threadIdx.x;
    float* p = v + (size_t)b * LSEQ * H + h;
    float acc = 0.0f;
    for (int l = 0; l < LSEQ; l += 4) {
        float a0 = p[(size_t)(l + 0) * H];
        float a1 = p[(size_t)(l + 1) * H];
        float a2 = p[(size_t)(l + 2) * H];
        float a3 = p[(size_t)(l + 3) * H];
        acc += a0; p[(size_t)(l + 0) * H] = acc * (1.0f / (float)(l + 1));
        acc += a1; p[(size_t)(l + 1) * H] = acc * (1.0f / (float)(l + 2));
        acc += a2; p[(size_t)(l + 2) * H] = acc * (1.0f / (float)(l + 3));
        acc += a3; p[(size_t)(l + 3) * H] = acc * (1.0f / (float)(l + 4));
    }
}

// ---------------- small MFMA GEMM (H x H weights) ----------------
template<int BIAS, int RELU, int WF32, int WBF16>
__global__ __launch_bounds__(256) void k_gemm64(
    const unsigned short* __restrict__ A,
    const unsigned short* __restrict__ Bmat,
    const float* __restrict__ bias,
    float* __restrict__ outF,
    unsigned short* __restrict__ outB,
    int N, int K) {
    int bm = blockIdx.x * 64;
    int bn = blockIdx.y * 64;
    int tid = threadIdx.x;
    int w = tid >> 6, l = tid & 63;
    int wr = (w >> 1) * 32, wc = (w & 1) * 32;
    int l16 = l & 15, lk = (l >> 4) * 8;

    const unsigned short* Ap = A + (size_t)(bm + wr + l16) * K + lk;
    const unsigned short* Bp = Bmat + (size_t)(bn + wc + l16) * K + lk;

    f32x4 acc00 = {0.f,0.f,0.f,0.f}, acc01 = {0.f,0.f,0.f,0.f};
    f32x4 acc10 = {0.f,0.f,0.f,0.f}, acc11 = {0.f,0.f,0.f,0.f};

#pragma unroll
    for (int k0 = 0; k0 < 256; k0 += 32) {
        short8 a0 = *(const short8*)(Ap + k0);
        short8 a1 = *(const short8*)(Ap + (size_t)16 * K + k0);
        short8 b0 = *(const short8*)(Bp + k0);
        short8 b1 = *(const short8*)(Bp + (size_t)16 * K + k0);
        acc00 = __builtin_amdgcn_mfma_f32_16x16x32_bf16(a0, b0, acc00, 0, 0, 0);
        acc01 = __builtin_amdgcn_mfma_f32_16x16x32_bf16(a0, b1, acc01, 0, 0, 0);
        acc10 = __builtin_amdgcn_mfma_f32_16x16x32_bf16(a1, b0, acc10, 0, 0, 0);
        acc11 = __builtin_amdgcn_mfma_f32_16x16x32_bf16(a1, b1, acc11, 0, 0, 0);
    }

    int r0 = (l >> 4) * 4;
#pragma unroll
    for (int i = 0; i < 2; ++i) {
#pragma unroll
        for (int j = 0; j < 2; ++j) {
            f32x4 a = (i == 0) ? (j == 0 ? acc00 : acc01) : (j == 0 ? acc10 : acc11);
            int col = bn + wc + j * 16 + l16;
            float bv = BIAS ? bias[col] : 0.0f;
            int rowb = bm + wr + i * 16 + r0;
#pragma unroll
            for (int r = 0; r < 4; ++r) {
                float vv = a[r] + bv;
                if (RELU) vv = fmaxf(vv, 0.0f);
                size_t idx = (size_t)(rowb + r) * N + col;
                if (WF32) outF[idx] = vv;
                if (WBF16) outB[idx] = f2bf(vv);
            }
        }
    }
}

// ---------------- logits GEMM: one 128x64 tile per block, N-fast XCD chunks ----
// R9 structure (stores only in epilogue, B->LDS once, A->VGPR, one barrier)
// with the work->XCD map changed to N-FAST within each XCD chunk:
// the ~96 concurrently-resident blocks of an XCD write ADJACENT 256B row
// segments into the SAME L2, completing each other's partial 128B lines
// before eviction (output row stride 200004B is only 4B-aligned, so segment
// edges are partial lines; cross-XCD or time-separated neighbors can't merge).
#define LGM 25                       // 3200 / 128
#define LGN 782                      // NPAD / 64
#define LGWG (LGM * LGN)             // 19550

__global__ __launch_bounds__(256, 3) void k_logits(
    const unsigned short* __restrict__ A,   // BL x 256 bf16
    const unsigned short* __restrict__ B,   // NPAD x 256 bf16
    float* __restrict__ out) {              // BL x V1 f32
    __shared__ unsigned short lB[64 * 256];  // 32KB

    // bijective XCD chunking (m204): xcd = orig&7 gets a CONTIGUOUS range of
    // g = mi*782 + ni  ->  within an XCD, consecutive blocks are ni-adjacent.
    int orig = blockIdx.x;
    int q = LGWG >> 3, r = LGWG & 7;     // q=2443, r=6
    int xcd = orig & 7, sub = orig >> 3;
    int g = (xcd < r ? xcd * (q + 1) : r * (q + 1) + (xcd - r) * q) + sub;
    int mi = g / LGN, ni = g % LGN;      // N fast within chunk
    int bm = mi * 128, n0 = ni * 64;

    int tid = threadIdx.x;
    int w = tid >> 6, l = tid & 63;
    int wr = w * 32;                     // wave's 32 rows of the 128-row tile
    int l16 = l & 15, lc = l >> 4;

    // stage B tile: 64 rows x 32 chunks(16B). dest linear, source chunk-XOR'd.
#pragma unroll
    for (int it = 0; it < 8; ++it) {
        int idx = it * 256 + tid;
        int row = idx >> 5;
        int cd = idx & 31;
        int cs = cd ^ (row & 7);
        const unsigned short* gp = B + (size_t)(n0 + row) * 256 + cs * 8;
        unsigned short* lp = &lB[(idx & ~63) * 8];   // wave-uniform base
        __builtin_amdgcn_global_load_lds((const GAS unsigned int*)gp,
                                         (LAS unsigned int*)lp, 16, 0, 0);
    }

    // A tile -> VGPRs (overlaps B staging; both drained by the one barrier)
    short8 af[2][8];
    {
        const unsigned short* Abase = A + (size_t)(bm + wr + l16) * 256 + lc * 8;
#pragma unroll
        for (int i = 0; i < 2; ++i)
#pragma unroll
            for (int kt = 0; kt < 8; ++kt)
                af[i][kt] = *(const short8*)(Abase + (size_t)(i * 16) * 256 + kt * 32);
    }
    __syncthreads();   // the ONLY barrier: no stores exist yet, nothing re-drained

    f32x4 acc[2][4] = {};
#pragma unroll
    for (int kt = 0; kt < 8; ++kt) {
        short8 bf[4];
#pragma unroll
        for (int j = 0; j < 4; ++j) {
            int row = j * 16 + l16;
            int pc = (kt * 4 + lc) ^ (row & 7);
            bf[j] = *(const short8*)&lB[row * 256 + pc * 8];
        }
#pragma unroll
        for (int i = 0; i < 2; ++i)
#pragma unroll
            for (int j = 0; j < 4; ++j)
                acc[i][j] = __builtin_amdgcn_mfma_f32_16x16x32_bf16(
                    af[i][kt], bf[j], acc[i][j], 0, 0, 0);
    }

    // epilogue: the block's only stores; per row, this block writes 256B
    // (n0..n0+63); the ni+1 neighbor (same XCD, concurrent) completes the
    // edge lines in L2.
#pragma unroll
    for (int i = 0; i < 2; ++i) {
        int mrow = bm + wr + i * 16 + lc * 4;
#pragma unroll
        for (int j = 0; j < 4; ++j) {
            int n = n0 + j * 16 + l16;
            if (n < V1) {
#pragma unroll
                for (int rg = 0; rg < 4; ++rg)
                    out[(size_t)(mrow + rg) * V1 + n] = acc[i][j][rg];
            }
        }
    }
}

// ---------------- driver ----------------

extern "C" void kernel_launch(void* const* d_in, const int* in_sizes, int n_in,
                              void* d_out, int out_size, void* d_ws, size_t ws_size,
                              hipStream_t stream) {
    const int*   ids      = (const int*)d_in[0];
    const float* item_emb = (const float*)d_in[1];
    const float* pos_emb  = (const float*)d_in[2];
    const float* emb_g    = (const float*)d_in[3];
    const float* emb_b    = (const float*)d_in[4];
    const float* Wv       = (const float*)d_in[5];
    const float* Wo       = (const float*)d_in[6];
    const float* attn_g   = (const float*)d_in[7];
    const float* attn_b   = (const float*)d_in[8];
    const float* W1       = (const float*)d_in[9];
    const float* b1       = (const float*)d_in[10];
    const float* W2       = (const float*)d_in[11];
    const float* b2       = (const float*)d_in[12];
    const float* ffn_g    = (const float*)d_in[13];
    const float* ffn_b    = (const float*)d_in[14];
    float* out = (float*)d_out;

    char* ws = (char*)d_ws;
    size_t off = 0;
    auto alloc = [&](size_t bytes) -> void* {
        void* p = ws + off;
        off += (bytes + 255) & ~(size_t)255;
        return p;
    };
    float* xf  = (float*)alloc((size_t)BL * H * 4);
    float* vbuf= (float*)alloc((size_t)BL * H * 4);
    float* y2  = (float*)alloc((size_t)BL * H * 4);
    unsigned short* xb  = (unsigned short*)alloc((size_t)BL * H * 2);
    unsigned short* y1b = (unsigned short*)alloc((size_t)BL * H * 2);
    unsigned short* WcB = (unsigned short*)alloc((size_t)2 * H * H * 2);
    unsigned short* W1B = (unsigned short*)alloc((size_t)2 * H * H * 2);
    unsigned short* W2B = (unsigned short*)alloc((size_t)2 * H * H * 2);
    unsigned short* WoB = (unsigned short*)alloc((size_t)2 * H * H * 2);
    unsigned short* WvT = (unsigned short*)alloc((size_t)2 * H * H * 2);
    unsigned short* embB= (unsigned short*)alloc((size_t)NPAD * H * 2);

    // --- prep ---
    k_f32_to_bf16<<<dim3(512), dim3(256), 0, stream>>>(W1, W1B, 2 * H * H);
    k_f32_to_bf16<<<dim3(512), dim3(256), 0, stream>>>(W2, W2B, 2 * H * H);
    k_f32_to_bf16<<<dim3(512), dim3(256), 0, stream>>>(Wo, WoB, 2 * H * H);
    k_transpose_bf<<<dim3(8, 8, 2), dim3(256), 0, stream>>>(Wv, WvT);
    {
        int n4 = NPAD * H / 4;
        k_conv_emb<<<dim3((n4 + 255) / 256), dim3(256), 0, stream>>>(item_emb, embB);
    }
    // Wc[i] = Wo[i] @ Wv[i]  via gemm64: A=WoB (o,m), B=WvT (h,m)
    for (int i = 0; i < 2; ++i)
        k_gemm64<0,0,0,1><<<dim3(4, 4), dim3(256), 0, stream>>>(
            WoB + (size_t)i * H * H, WvT + (size_t)i * H * H, nullptr,
            nullptr, WcB + (size_t)i * H * H, H, H);

    // --- embedding + LN ---
    k_embed_ln<<<dim3(BL), dim3(H), 0, stream>>>(ids, item_emb, pos_emb, emb_g, emb_b, xf, xb);

    // --- transformer blocks ---
    for (int i = 0; i < 2; ++i) {
        k_gemm64<0,0,1,0><<<dim3(BL / 64, H / 64), dim3(256), 0, stream>>>(
            xb, WcB + (size_t)i * H * H, nullptr, vbuf, nullptr, H, H);
        k_cumsum<<<dim3(NB, 4), dim3(64), 0, stream>>>(vbuf);
        k_add_ln<<<dim3(BL), dim3(H), 0, stream>>>(
            xf, vbuf, attn_g + (size_t)i * H, attn_b + (size_t)i * H, ids, xf, xb);
        k_gemm64<1,1,0,1><<<dim3(BL / 64, H / 64), dim3(256), 0, stream>>>(
            xb, W1B + (size_t)i * H * H, b1 + (size_t)i * H, nullptr, y1b, H, H);
        k_gemm64<1,0,1,0><<<dim3(BL / 64, H / 64), dim3(256), 0, stream>>>(
            y1b, W2B + (size_t)i * H * H, b2 + (size_t)i * H, y2, nullptr, H, H);
        k_add_ln<<<dim3(BL), dim3(H), 0, stream>>>(
            xf, y2, ffn_g + (size_t)i * H, ffn_b + (size_t)i * H, ids, xf, xb);
    }

    // --- logits = x @ item_emb^T ---
    k_logits<<<dim3(LGWG), dim3(256), 0, stream>>>(xb, embB, out);
}